// Round 15
// baseline (181.644 us; speedup 1.0000x reference)
//
#include <hip/hip_runtime.h>

constexpr int N_NODES = 100000;
constexpr int F1 = 64;   // IN_DIM == HID_DIM
constexpr int F2 = 16;   // OUT_DIM
constexpr int SH = 7;                             // bin = dst >> 7
constexpr int NPB = 128;                          // nodes per bin
constexpr int NBINS = (N_NODES + NPB - 1) / NPB;  // 782
constexpr int CAPB = 2560;                        // mean 2046, +11 sigma
constexpr int TILE = 4096;                        // edges per k_bin block
constexpr int GSTRIDE = 16;                       // gcnt: one counter per 64B line

// bf16 helpers (RNE)
static __device__ __forceinline__ unsigned short f2bf(float f) {
    unsigned int u = __float_as_uint(f);
    unsigned int r = (u + 0x7fffu + ((u >> 16) & 1u)) >> 16;
    return (unsigned short)r;
}
static __device__ __forceinline__ float bf2f(unsigned short b) {
    return __uint_as_float(((unsigned int)b) << 16);
}

// ---------------- pass 1: coarse binning (block-aggregated allocation) ----------------
__global__ __launch_bounds__(512) void k_bin(const int* __restrict__ src,
                                             const int* __restrict__ dst, int E,
                                             unsigned int* __restrict__ gcnt,
                                             unsigned int* __restrict__ entries) {
    __shared__ unsigned int cnt[NBINS];
    __shared__ unsigned int cur[NBINS];
    int tid = threadIdx.x;
    int base = blockIdx.x * TILE;
    int end = min(base + TILE, E);
    for (int i = tid; i < NBINS; i += 512) cnt[i] = 0;
    __syncthreads();
    for (int e = base + tid; e < end; e += 512) atomicAdd(&cnt[dst[e] >> SH], 1u);
    __syncthreads();
    for (int i = tid; i < NBINS; i += 512) {
        unsigned int c = cnt[i];
        cur[i] = (unsigned int)i * CAPB + (c ? atomicAdd(&gcnt[i * GSTRIDE], c) : 0u);
    }
    __syncthreads();
    for (int e = base + tid; e < end; e += 512) {
        int d = dst[e];
        int s = src[e];
        int bb = d >> SH;
        unsigned int p = atomicAdd(&cur[bb], 1u);
        if (p - (unsigned int)bb * CAPB < CAPB)
            entries[p] = (unsigned int)s | ((unsigned int)(d & (NPB - 1)) << 17);
    }
}

// ---------------- hs = bf16((x @ W1) * dinv[row]); block = bin (128 rows), fused degree->dinv ----------------
__global__ __launch_bounds__(512) void k_xw1(const float* __restrict__ x,
                                             const float* __restrict__ W,
                                             const unsigned int* __restrict__ gcnt,
                                             const unsigned int* __restrict__ entries,
                                             float* __restrict__ dinv,
                                             unsigned short* __restrict__ hs) {
    constexpr int XS = 68;  // 2-way bank aliasing only (free)
    __shared__ float Ws[64 * 64];
    __shared__ float xs[128 * XS];
    __shared__ unsigned int ncnt[NPB];
    __shared__ float dinvs[NPB];
    int tid = threadIdx.x;
    int b = blockIdx.x;
    int r0 = b * NPB;
    for (int i = tid; i < 1024; i += 512) {
        int k = i >> 4, c4 = (i & 15) << 2;
        *(float4*)&Ws[k * 64 + c4] = *(const float4*)&W[k * 64 + c4];
    }
    for (int i = tid; i < 2048; i += 512) {
        int rr = i >> 4, c4 = (i & 15) << 2;
        int r = r0 + rr;
        float4 v = make_float4(0.f, 0.f, 0.f, 0.f);
        if (r < N_NODES) v = *(const float4*)&x[(size_t)r * 64 + c4];
        *(float4*)&xs[rr * XS + c4] = v;
    }
    if (tid < NPB) ncnt[tid] = 0;
    __syncthreads();
    unsigned int cntE = gcnt[b * GSTRIDE]; if (cntE > CAPB) cntE = CAPB;
    unsigned int ebase = (unsigned int)b * CAPB;
    for (unsigned int e = tid; e < cntE; e += 512)
        atomicAdd(&ncnt[entries[ebase + e] >> 17], 1u);
    __syncthreads();
    if (tid < NPB) {
        int node = r0 + tid;
        float dv = rsqrtf((float)(ncnt[tid] + 1u));
        dinvs[tid] = dv;
        if (node < N_NODES) dinv[node] = dv;
    }
    __syncthreads();
    int tx = tid & 15, ty = tid >> 4;
    int c0 = tx << 2, rb = ty << 2;
    float acc[4][4] = {};
#pragma unroll 8
    for (int k = 0; k < 64; ++k) {
        float4 w = *(float4*)&Ws[k * 64 + c0];
        float x0 = xs[(rb + 0) * XS + k];
        float x1 = xs[(rb + 1) * XS + k];
        float x2 = xs[(rb + 2) * XS + k];
        float x3 = xs[(rb + 3) * XS + k];
        acc[0][0] += x0 * w.x; acc[0][1] += x0 * w.y; acc[0][2] += x0 * w.z; acc[0][3] += x0 * w.w;
        acc[1][0] += x1 * w.x; acc[1][1] += x1 * w.y; acc[1][2] += x1 * w.z; acc[1][3] += x1 * w.w;
        acc[2][0] += x2 * w.x; acc[2][1] += x2 * w.y; acc[2][2] += x2 * w.z; acc[2][3] += x2 * w.w;
        acc[3][0] += x3 * w.x; acc[3][1] += x3 * w.y; acc[3][2] += x3 * w.z; acc[3][3] += x3 * w.w;
    }
#pragma unroll
    for (int i = 0; i < 4; ++i) {
        int r = r0 + rb + i;
        if (r >= N_NODES) break;
        float dv = dinvs[rb + i];
        ushort4 p;
        p.x = f2bf(acc[i][0] * dv);
        p.y = f2bf(acc[i][1] * dv);
        p.z = f2bf(acc[i][2] * dv);
        p.w = f2bf(acc[i][3] * dv);
        *(ushort4*)&hs[(size_t)r * 64 + c0] = p;
    }
}

// ---------------- layer-1: XCD feature-split. 2 blocks/bin; each handles 32 feats ----------------
// Mapping: xcd = blk%8 (round-robin heuristic); xcd 0-3 -> half 0 (feats 0-31),
// xcd 4-7 -> half 1 (feats 32-63); bin = (blk>>3)*4 + (blk&3).
// Each XCD then fetches only its half's 64B sector of each hs row -> per-XCD footprint halves.
// half 0 also persists sorted CSR (separate buffer; entries stays read-only) for agg2.
__global__ __launch_bounds__(1024) void k_agg1f(const unsigned int* __restrict__ gcnt,
                                                const unsigned int* __restrict__ entries,
                                                unsigned int* __restrict__ sorted,
                                                unsigned int* __restrict__ noffg,
                                                const unsigned short* __restrict__ hs,
                                                const float* __restrict__ dinv,
                                                unsigned short* __restrict__ out1) {
    __shared__ unsigned int ncnt[NPB];
    __shared__ unsigned int noff[NPB + 1];
    __shared__ unsigned int cur[NPB];
    __shared__ unsigned int sl[CAPB];
    int tid = threadIdx.x;
    int blk = blockIdx.x;
    int half = (blk & 7) >= 4;
    int b = ((blk >> 3) << 2) + (blk & 3);
    if (b >= NBINS) return;
    unsigned int cntE = gcnt[b * GSTRIDE]; if (cntE > CAPB) cntE = CAPB;
    unsigned int base = (unsigned int)b * CAPB;
    if (tid < NPB) ncnt[tid] = 0;
    __syncthreads();
    for (unsigned int e = tid; e < cntE; e += 1024)
        atomicAdd(&ncnt[entries[base + e] >> 17], 1u);
    __syncthreads();
    if (tid < NPB) cur[tid] = ncnt[tid];
    __syncthreads();
    for (int ofs = 1; ofs < NPB; ofs <<= 1) {
        unsigned int v = (tid < NPB && tid >= ofs) ? cur[tid - ofs] : 0u;
        __syncthreads();
        if (tid < NPB) cur[tid] += v;
        __syncthreads();
    }
    if (tid < NPB) noff[tid + 1] = cur[tid];
    if (tid == 0) noff[0] = 0;
    __syncthreads();
    if (tid < NPB) cur[tid] = noff[tid];
    __syncthreads();
    for (unsigned int e = tid; e < cntE; e += 1024) {
        unsigned int v = entries[base + e];
        unsigned int p = atomicAdd(&cur[v >> 17], 1u);
        sl[p] = v & 0x1FFFFu;
    }
    __syncthreads();
    if (half == 0) {  // persist sorted CSR once per bin (agg2 consumes)
        for (unsigned int e = tid; e < cntE; e += 1024) sorted[base + e] = sl[e];
        if (tid <= NPB) noffg[b * (NPB + 1) + tid] = noff[tid];
    }
    int wid = tid >> 6, lane = tid & 63;
    int grp = lane >> 5;              // edge group 0/1 (2 edges per wave-instr)
    int c = half * 32 + (lane & 31);  // absolute feature column
    for (int n = wid; n < NPB; n += 16) {
        int node = b * NPB + n;
        if (node >= N_NODES) break;  // uniform per wave
        unsigned int j = noff[n] + (unsigned)grp, jend = noff[n + 1];
        float acc = grp ? 0.f : bf2f(hs[(size_t)node * 64 + c]);  // self-loop once
        for (; j + 6 < jend; j += 8) {  // 4 gathers in flight per group = 8 edges/iter/wave
            unsigned int s0 = sl[j], s1 = sl[j + 2], s2 = sl[j + 4], s3 = sl[j + 6];
            float a0 = bf2f(hs[(size_t)s0 * 64 + c]);
            float a1 = bf2f(hs[(size_t)s1 * 64 + c]);
            float a2 = bf2f(hs[(size_t)s2 * 64 + c]);
            float a3 = bf2f(hs[(size_t)s3 * 64 + c]);
            acc += (a0 + a1) + (a2 + a3);
        }
        for (; j < jend; j += 2) acc += bf2f(hs[(size_t)sl[j] * 64 + c]);
        acc += __shfl_xor(acc, 32);  // combine the two edge groups
        if (lane < 32)
            out1[(size_t)node * 64 + c] = f2bf(acc * dinv[node]);
    }
}

// ---------------- h2s = bf16(relu(out1 + b1) @ W2 * dinv[row]) — register-tiled 2x4 ----------------
__global__ __launch_bounds__(256) void k_xw2(const unsigned short* __restrict__ out1,
                                             const float* __restrict__ b1,
                                             const float* __restrict__ W2,
                                             const float* __restrict__ dinv,
                                             unsigned short* __restrict__ h2s) {
    constexpr int RS = 66;
    __shared__ float Ws[64 * 16];
    __shared__ float rs[128 * RS];
    __shared__ float b1s[64];
    int tid = threadIdx.x;
    int r0 = blockIdx.x * 128;
    if (tid < 64) b1s[tid] = b1[tid];
    for (int i = tid; i < 256; i += 256)
        *(float4*)&Ws[i * 4] = *(const float4*)&W2[i * 4];
    __syncthreads();
    for (int i = tid; i < 2048; i += 256) {
        int rr = i >> 4, c4 = (i & 15) << 2;
        int r = r0 + rr;
        float v0 = 0.f, v1 = 0.f, v2 = 0.f, v3 = 0.f;
        if (r < N_NODES) {
            ushort4 u = *(const ushort4*)&out1[(size_t)r * 64 + c4];
            v0 = fmaxf(bf2f(u.x) + b1s[c4 + 0], 0.f);
            v1 = fmaxf(bf2f(u.y) + b1s[c4 + 1], 0.f);
            v2 = fmaxf(bf2f(u.z) + b1s[c4 + 2], 0.f);
            v3 = fmaxf(bf2f(u.w) + b1s[c4 + 3], 0.f);
        }
        float* pp = &rs[rr * RS + c4];
        pp[0] = v0; pp[1] = v1; pp[2] = v2; pp[3] = v3;
    }
    __syncthreads();
    int tx = tid & 3, ty = tid >> 2;
    int c0 = tx << 2, rb = ty << 1;
    float acc[2][4] = {};
#pragma unroll 8
    for (int k = 0; k < 64; ++k) {
        float4 w = *(float4*)&Ws[k * 16 + c0];
        float x0 = rs[(rb + 0) * RS + k];
        float x1 = rs[(rb + 1) * RS + k];
        acc[0][0] += x0 * w.x; acc[0][1] += x0 * w.y; acc[0][2] += x0 * w.z; acc[0][3] += x0 * w.w;
        acc[1][0] += x1 * w.x; acc[1][1] += x1 * w.y; acc[1][2] += x1 * w.z; acc[1][3] += x1 * w.w;
    }
#pragma unroll
    for (int i = 0; i < 2; ++i) {
        int r = r0 + rb + i;
        if (r >= N_NODES) break;
        float dv = dinv[r];
        ushort4 p;
        p.x = f2bf(acc[i][0] * dv);
        p.y = f2bf(acc[i][1] * dv);
        p.z = f2bf(acc[i][2] * dv);
        p.w = f2bf(acc[i][3] * dv);
        *(ushort4*)&h2s[(size_t)r * 16 + c0] = p;
    }
}

// ---------------- layer-2: consume saved CSR (no rebuild); 16 feats x 4 edge slots ----------------
__global__ __launch_bounds__(1024) void k_agg2f(const unsigned int* __restrict__ gcnt,
                                                const unsigned int* __restrict__ sorted,
                                                const unsigned int* __restrict__ noffg,
                                                const unsigned short* __restrict__ h2s,
                                                const float* __restrict__ dinv,
                                                const float* __restrict__ b2,
                                                float* __restrict__ out) {
    __shared__ unsigned int noff[NPB + 1];
    __shared__ unsigned int sl[CAPB];
    int tid = threadIdx.x;
    int b = blockIdx.x;
    unsigned int cntE = gcnt[b * GSTRIDE]; if (cntE > CAPB) cntE = CAPB;
    unsigned int base = (unsigned int)b * CAPB;
    if (tid <= NPB) noff[tid] = noffg[b * (NPB + 1) + tid];
    for (unsigned int e = tid; e < cntE; e += 1024) sl[e] = sorted[base + e];
    __syncthreads();
    int wid = tid >> 6, lane = tid & 63;
    int k = lane & 15, esub = lane >> 4;
    for (int n = wid; n < NPB; n += 16) {
        int node = b * NPB + n;
        if (node >= N_NODES) break;  // uniform per wave
        unsigned int j0 = noff[n], jend = noff[n + 1];
        float acc = 0.0f;
        unsigned int j = j0 + esub;
        for (; j + 4 < jend; j += 8) {
            float a = bf2f(h2s[(size_t)sl[j] * 16 + k]);
            float c = bf2f(h2s[(size_t)sl[j + 4] * 16 + k]);
            acc += a + c;
        }
        if (j < jend) acc += bf2f(h2s[(size_t)sl[j] * 16 + k]);
        acc += __shfl_xor(acc, 16);
        acc += __shfl_xor(acc, 32);
        if (lane < 16)
            out[(size_t)node * 16 + k] = (acc + bf2f(h2s[(size_t)node * 16 + k])) * dinv[node] + b2[k];
    }
}

static inline size_t align256(size_t x) { return (x + 255) & ~size_t(255); }

extern "C" void kernel_launch(void* const* d_in, const int* in_sizes, int n_in,
                              void* d_out, int out_size, void* d_ws, size_t ws_size,
                              hipStream_t stream) {
    const float* x  = (const float*)d_in[0];
    const int* edge = (const int*)d_in[1];
    const float* W1 = (const float*)d_in[2];
    const float* b1 = (const float*)d_in[3];
    const float* W2 = (const float*)d_in[4];
    const float* b2 = (const float*)d_in[5];
    float* out = (float*)d_out;

    const int E = in_sizes[1] / 2;
    const int* src = edge;
    const int* dst = edge + E;

    // workspace layout (~46 MB)
    char* ws = (char*)d_ws;
    size_t o = 0;
    unsigned int* gcnt    = (unsigned int*)(ws + o); o += align256((size_t)NBINS * GSTRIDE * 4);
    float* dinv           = (float*)(ws + o);        o += align256((size_t)N_NODES * 4);
    unsigned int* entries = (unsigned int*)(ws + o); o += align256((size_t)NBINS * CAPB * 4);
    unsigned int* sorted  = (unsigned int*)(ws + o); o += align256((size_t)NBINS * CAPB * 4);
    unsigned int* noffg   = (unsigned int*)(ws + o); o += align256((size_t)NBINS * (NPB + 1) * 4);
    unsigned short* hs    = (unsigned short*)(ws + o); o += align256((size_t)N_NODES * F1 * 2);
    unsigned short* out1  = (unsigned short*)(ws + o); o += align256((size_t)N_NODES * F1 * 2);
    unsigned short* h2s   = (unsigned short*)(ws + o); o += align256((size_t)N_NODES * F2 * 2);

    hipMemsetAsync(gcnt, 0, (size_t)NBINS * GSTRIDE * 4, stream);

    k_bin<<<(E + TILE - 1) / TILE, 512, 0, stream>>>(src, dst, E, gcnt, entries);

    // layer 1 (dinv fused into k_xw1; agg1 XCD-feature-split, persists sorted CSR)
    k_xw1<<<NBINS, 512, 0, stream>>>(x, W1, gcnt, entries, dinv, hs);
    {
        int halfblocks = ((2 * NBINS + 7) / 8) * 8;  // 1568: keep blk%8 mapping exact
        k_agg1f<<<halfblocks, 1024, 0, stream>>>(gcnt, entries, sorted, noffg, hs, dinv, out1);
    }

    // layer 2 (agg2 consumes saved CSR)
    k_xw2<<<(N_NODES + 127) / 128, 256, 0, stream>>>(out1, b1, W2, dinv, h2s);
    k_agg2f<<<NBINS, 1024, 0, stream>>>(gcnt, sorted, noffg, h2s, dinv, b2, out);
}

// Round 16
// 136.426 us; speedup vs baseline: 1.3315x; 1.3315x over previous
//
#include <hip/hip_runtime.h>

constexpr int N_NODES = 100000;
constexpr int F1 = 64;   // IN_DIM == HID_DIM
constexpr int F2 = 16;   // OUT_DIM
constexpr int SH = 7;                             // bin = dst >> 7
constexpr int NPB = 128;                          // nodes per bin
constexpr int NBINS = (N_NODES + NPB - 1) / NPB;  // 782
constexpr int CAPB = 2560;                        // mean 2046, +11 sigma
constexpr int TILE = 8192;                        // edges per k_bin block
constexpr int GSTRIDE = 16;                       // gcnt: one counter per 64B line

// bf16 helpers (RNE)
static __device__ __forceinline__ unsigned short f2bf(float f) {
    unsigned int u = __float_as_uint(f);
    unsigned int r = (u + 0x7fffu + ((u >> 16) & 1u)) >> 16;
    return (unsigned short)r;
}
static __device__ __forceinline__ float bf2f(unsigned short b) {
    return __uint_as_float(((unsigned int)b) << 16);
}

// ---------------- pass 1: binning with block-local sort + coalesced flush ----------------
// Each block: 8 edges/thread in registers -> LDS hist -> scan -> LDS-sorted staging ->
// ordered flush (consecutive slots of a bin -> consecutive global addrs -> full-line stores).
__global__ __launch_bounds__(1024) void k_bin(const int* __restrict__ src,
                                              const int* __restrict__ dst, int E,
                                              unsigned int* __restrict__ gcnt,
                                              unsigned int* __restrict__ entries) {
    __shared__ unsigned int cnt[NBINS];        // hist -> scan scratch -> cursor
    __shared__ unsigned int gbase[NBINS];      // global base - local base
    __shared__ unsigned int ebuf[TILE];        // locally sorted entries
    __shared__ unsigned short pbin[TILE];      // bin of each sorted slot
    int tid = threadIdx.x;
    int base = blockIdx.x * TILE;
    int end = min(base + TILE, E);
    int tcount = end - base;
    // load up to 8 edges into registers
    int e0 = base + tid * 8;
    int nle = e0 < end ? min(8, end - e0) : 0;
    int ds[8], ss[8];
#pragma unroll
    for (int i = 0; i < 8; ++i) {
        if (i < nle) { ds[i] = dst[e0 + i]; ss[i] = src[e0 + i]; }
    }
    for (int i = tid; i < NBINS; i += 1024) cnt[i] = 0;
    __syncthreads();
#pragma unroll
    for (int i = 0; i < 8; ++i)
        if (i < nle) atomicAdd(&cnt[ds[i] >> SH], 1u);
    __syncthreads();
    // inclusive scan over NBINS (1024 threads, Hillis-Steele)
    unsigned int ccount = (tid < NBINS) ? cnt[tid] : 0u;
    for (int ofs = 1; ofs < 1024; ofs <<= 1) {
        unsigned int v = (tid < NBINS && tid >= ofs) ? cnt[tid - ofs] : 0u;
        __syncthreads();
        if (tid < NBINS) cnt[tid] += v;
        __syncthreads();
    }
    if (tid < NBINS) {
        unsigned int excl = cnt[tid] - ccount;
        unsigned int alloc = ccount ? atomicAdd(&gcnt[tid * GSTRIDE], ccount) : 0u;
        gbase[tid] = (unsigned int)tid * CAPB + alloc - excl;
        cnt[tid] = excl;  // becomes scatter cursor
    }
    __syncthreads();
    // scatter into local sorted staging
#pragma unroll
    for (int i = 0; i < 8; ++i) {
        if (i < nle) {
            int d = ds[i];
            int b = d >> SH;
            unsigned int p = atomicAdd(&cnt[b], 1u);
            ebuf[p] = (unsigned int)ss[i] | ((unsigned int)(d & (NPB - 1)) << 17);
            pbin[p] = (unsigned short)b;
        }
    }
    __syncthreads();
    // ordered flush: consecutive p of same bin -> consecutive global positions
    for (int p = tid; p < tcount; p += 1024) {
        unsigned int b = pbin[p];
        unsigned int gpos = gbase[b] + (unsigned int)p;
        if (gpos - b * CAPB < CAPB) entries[gpos] = ebuf[p];
    }
}

// ---------------- hs = bf16((x @ W1) * dinv[row]); block = bin (128 rows), fused degree->dinv ----------------
__global__ __launch_bounds__(512) void k_xw1(const float* __restrict__ x,
                                             const float* __restrict__ W,
                                             const unsigned int* __restrict__ gcnt,
                                             const unsigned int* __restrict__ entries,
                                             float* __restrict__ dinv,
                                             unsigned short* __restrict__ hs) {
    constexpr int XS = 68;  // 2-way bank aliasing only (free)
    __shared__ float Ws[64 * 64];
    __shared__ float xs[128 * XS];
    __shared__ unsigned int ncnt[NPB];
    __shared__ float dinvs[NPB];
    int tid = threadIdx.x;
    int b = blockIdx.x;
    int r0 = b * NPB;
    for (int i = tid; i < 1024; i += 512) {
        int k = i >> 4, c4 = (i & 15) << 2;
        *(float4*)&Ws[k * 64 + c4] = *(const float4*)&W[k * 64 + c4];
    }
    for (int i = tid; i < 2048; i += 512) {
        int rr = i >> 4, c4 = (i & 15) << 2;
        int r = r0 + rr;
        float4 v = make_float4(0.f, 0.f, 0.f, 0.f);
        if (r < N_NODES) v = *(const float4*)&x[(size_t)r * 64 + c4];
        *(float4*)&xs[rr * XS + c4] = v;
    }
    if (tid < NPB) ncnt[tid] = 0;
    __syncthreads();
    unsigned int cntE = gcnt[b * GSTRIDE]; if (cntE > CAPB) cntE = CAPB;
    unsigned int ebase = (unsigned int)b * CAPB;
    for (unsigned int e = tid; e < cntE; e += 512)
        atomicAdd(&ncnt[entries[ebase + e] >> 17], 1u);
    __syncthreads();
    if (tid < NPB) {
        int node = r0 + tid;
        float dv = rsqrtf((float)(ncnt[tid] + 1u));
        dinvs[tid] = dv;
        if (node < N_NODES) dinv[node] = dv;
    }
    __syncthreads();
    int tx = tid & 15, ty = tid >> 4;
    int c0 = tx << 2, rb = ty << 2;
    float acc[4][4] = {};
#pragma unroll 8
    for (int k = 0; k < 64; ++k) {
        float4 w = *(float4*)&Ws[k * 64 + c0];
        float x0 = xs[(rb + 0) * XS + k];
        float x1 = xs[(rb + 1) * XS + k];
        float x2 = xs[(rb + 2) * XS + k];
        float x3 = xs[(rb + 3) * XS + k];
        acc[0][0] += x0 * w.x; acc[0][1] += x0 * w.y; acc[0][2] += x0 * w.z; acc[0][3] += x0 * w.w;
        acc[1][0] += x1 * w.x; acc[1][1] += x1 * w.y; acc[1][2] += x1 * w.z; acc[1][3] += x1 * w.w;
        acc[2][0] += x2 * w.x; acc[2][1] += x2 * w.y; acc[2][2] += x2 * w.z; acc[2][3] += x2 * w.w;
        acc[3][0] += x3 * w.x; acc[3][1] += x3 * w.y; acc[3][2] += x3 * w.z; acc[3][3] += x3 * w.w;
    }
#pragma unroll
    for (int i = 0; i < 4; ++i) {
        int r = r0 + rb + i;
        if (r >= N_NODES) break;
        float dv = dinvs[rb + i];
        ushort4 p;
        p.x = f2bf(acc[i][0] * dv);
        p.y = f2bf(acc[i][1] * dv);
        p.z = f2bf(acc[i][2] * dv);
        p.w = f2bf(acc[i][3] * dv);
        *(ushort4*)&hs[(size_t)r * 64 + c0] = p;
    }
}

// ---------------- layer-1: LDS CSR build + aggregate; saves sorted CSR for agg2 ----------------
__global__ __launch_bounds__(1024) void k_agg1f(const unsigned int* __restrict__ gcnt,
                                                unsigned int* __restrict__ entries,  // overwritten with sorted
                                                unsigned int* __restrict__ noffg,
                                                const unsigned short* __restrict__ hs,
                                                const float* __restrict__ dinv,
                                                unsigned short* __restrict__ out1) {
    __shared__ unsigned int ncnt[NPB];
    __shared__ unsigned int noff[NPB + 1];
    __shared__ unsigned int cur[NPB];
    __shared__ unsigned int sl[CAPB];
    int tid = threadIdx.x;
    int b = blockIdx.x;
    unsigned int cntE = gcnt[b * GSTRIDE]; if (cntE > CAPB) cntE = CAPB;
    unsigned int base = (unsigned int)b * CAPB;
    if (tid < NPB) ncnt[tid] = 0;
    __syncthreads();
    for (unsigned int e = tid; e < cntE; e += 1024)
        atomicAdd(&ncnt[entries[base + e] >> 17], 1u);
    __syncthreads();
    if (tid < NPB) cur[tid] = ncnt[tid];
    __syncthreads();
    for (int ofs = 1; ofs < NPB; ofs <<= 1) {
        unsigned int v = (tid < NPB && tid >= ofs) ? cur[tid - ofs] : 0u;
        __syncthreads();
        if (tid < NPB) cur[tid] += v;
        __syncthreads();
    }
    if (tid < NPB) noff[tid + 1] = cur[tid];
    if (tid == 0) noff[0] = 0;
    __syncthreads();
    if (tid < NPB) cur[tid] = noff[tid];
    __syncthreads();
    for (unsigned int e = tid; e < cntE; e += 1024) {
        unsigned int v = entries[base + e];
        unsigned int p = atomicAdd(&cur[v >> 17], 1u);
        sl[p] = v & 0x1FFFFu;
    }
    __syncthreads();
    // persist sorted CSR (entries overwritten in place; safe after barrier)
    for (unsigned int e = tid; e < cntE; e += 1024) entries[base + e] = sl[e];
    if (tid <= NPB) noffg[b * (NPB + 1) + tid] = noff[tid];
    int wid = tid >> 6, k = tid & 63;
    for (int n = wid; n < NPB; n += 16) {
        int node = b * NPB + n;
        if (node >= N_NODES) break;  // uniform per wave
        unsigned int j = noff[n], jend = noff[n + 1];
        float acc = bf2f(hs[(size_t)node * 64 + k]);  // self-loop
        for (; j + 8 <= jend; j += 8) {
            unsigned int s0 = sl[j], s1 = sl[j + 1], s2 = sl[j + 2], s3 = sl[j + 3];
            unsigned int s4 = sl[j + 4], s5 = sl[j + 5], s6 = sl[j + 6], s7 = sl[j + 7];
            float a0 = bf2f(hs[(size_t)s0 * 64 + k]);
            float a1 = bf2f(hs[(size_t)s1 * 64 + k]);
            float a2 = bf2f(hs[(size_t)s2 * 64 + k]);
            float a3 = bf2f(hs[(size_t)s3 * 64 + k]);
            float a4 = bf2f(hs[(size_t)s4 * 64 + k]);
            float a5 = bf2f(hs[(size_t)s5 * 64 + k]);
            float a6 = bf2f(hs[(size_t)s6 * 64 + k]);
            float a7 = bf2f(hs[(size_t)s7 * 64 + k]);
            acc += ((a0 + a1) + (a2 + a3)) + ((a4 + a5) + (a6 + a7));
        }
        for (; j + 4 <= jend; j += 4) {
            unsigned int s0 = sl[j], s1 = sl[j + 1], s2 = sl[j + 2], s3 = sl[j + 3];
            float a0 = bf2f(hs[(size_t)s0 * 64 + k]);
            float a1 = bf2f(hs[(size_t)s1 * 64 + k]);
            float a2 = bf2f(hs[(size_t)s2 * 64 + k]);
            float a3 = bf2f(hs[(size_t)s3 * 64 + k]);
            acc += (a0 + a1) + (a2 + a3);
        }
        for (; j < jend; ++j) acc += bf2f(hs[(size_t)sl[j] * 64 + k]);
        out1[(size_t)node * 64 + k] = f2bf(acc * dinv[node]);
    }
}

// ---------------- h2s = bf16(relu(out1 + b1) @ W2 * dinv[row]) — register-tiled 2x4 ----------------
__global__ __launch_bounds__(256) void k_xw2(const unsigned short* __restrict__ out1,
                                             const float* __restrict__ b1,
                                             const float* __restrict__ W2,
                                             const float* __restrict__ dinv,
                                             unsigned short* __restrict__ h2s) {
    constexpr int RS = 66;
    __shared__ float Ws[64 * 16];
    __shared__ float rs[128 * RS];
    __shared__ float b1s[64];
    int tid = threadIdx.x;
    int r0 = blockIdx.x * 128;
    if (tid < 64) b1s[tid] = b1[tid];
    for (int i = tid; i < 256; i += 256)
        *(float4*)&Ws[i * 4] = *(const float4*)&W2[i * 4];
    __syncthreads();
    for (int i = tid; i < 2048; i += 256) {
        int rr = i >> 4, c4 = (i & 15) << 2;
        int r = r0 + rr;
        float v0 = 0.f, v1 = 0.f, v2 = 0.f, v3 = 0.f;
        if (r < N_NODES) {
            ushort4 u = *(const ushort4*)&out1[(size_t)r * 64 + c4];
            v0 = fmaxf(bf2f(u.x) + b1s[c4 + 0], 0.f);
            v1 = fmaxf(bf2f(u.y) + b1s[c4 + 1], 0.f);
            v2 = fmaxf(bf2f(u.z) + b1s[c4 + 2], 0.f);
            v3 = fmaxf(bf2f(u.w) + b1s[c4 + 3], 0.f);
        }
        float* pp = &rs[rr * RS + c4];
        pp[0] = v0; pp[1] = v1; pp[2] = v2; pp[3] = v3;
    }
    __syncthreads();
    int tx = tid & 3, ty = tid >> 2;
    int c0 = tx << 2, rb = ty << 1;
    float acc[2][4] = {};
#pragma unroll 8
    for (int k = 0; k < 64; ++k) {
        float4 w = *(float4*)&Ws[k * 16 + c0];
        float x0 = rs[(rb + 0) * RS + k];
        float x1 = rs[(rb + 1) * RS + k];
        acc[0][0] += x0 * w.x; acc[0][1] += x0 * w.y; acc[0][2] += x0 * w.z; acc[0][3] += x0 * w.w;
        acc[1][0] += x1 * w.x; acc[1][1] += x1 * w.y; acc[1][2] += x1 * w.z; acc[1][3] += x1 * w.w;
    }
#pragma unroll
    for (int i = 0; i < 2; ++i) {
        int r = r0 + rb + i;
        if (r >= N_NODES) break;
        float dv = dinv[r];
        ushort4 p;
        p.x = f2bf(acc[i][0] * dv);
        p.y = f2bf(acc[i][1] * dv);
        p.z = f2bf(acc[i][2] * dv);
        p.w = f2bf(acc[i][3] * dv);
        *(ushort4*)&h2s[(size_t)r * 16 + c0] = p;
    }
}

// ---------------- layer-2: consume saved CSR (no rebuild); 16 feats x 4 edge slots ----------------
__global__ __launch_bounds__(1024) void k_agg2f(const unsigned int* __restrict__ gcnt,
                                                const unsigned int* __restrict__ sorted,  // = entries (sorted)
                                                const unsigned int* __restrict__ noffg,
                                                const unsigned short* __restrict__ h2s,
                                                const float* __restrict__ dinv,
                                                const float* __restrict__ b2,
                                                float* __restrict__ out) {
    __shared__ unsigned int noff[NPB + 1];
    __shared__ unsigned int sl[CAPB];
    int tid = threadIdx.x;
    int b = blockIdx.x;
    unsigned int cntE = gcnt[b * GSTRIDE]; if (cntE > CAPB) cntE = CAPB;
    unsigned int base = (unsigned int)b * CAPB;
    if (tid <= NPB) noff[tid] = noffg[b * (NPB + 1) + tid];
    for (unsigned int e = tid; e < cntE; e += 1024) sl[e] = sorted[base + e];
    __syncthreads();
    int wid = tid >> 6, lane = tid & 63;
    int k = lane & 15, esub = lane >> 4;
    for (int n = wid; n < NPB; n += 16) {
        int node = b * NPB + n;
        if (node >= N_NODES) break;  // uniform per wave
        unsigned int j0 = noff[n], jend = noff[n + 1];
        float acc = 0.0f;
        unsigned int j = j0 + esub;
        for (; j + 4 < jend; j += 8) {
            float a = bf2f(h2s[(size_t)sl[j] * 16 + k]);
            float c = bf2f(h2s[(size_t)sl[j + 4] * 16 + k]);
            acc += a + c;
        }
        if (j < jend) acc += bf2f(h2s[(size_t)sl[j] * 16 + k]);
        acc += __shfl_xor(acc, 16);
        acc += __shfl_xor(acc, 32);
        if (lane < 16)
            out[(size_t)node * 16 + k] = (acc + bf2f(h2s[(size_t)node * 16 + k])) * dinv[node] + b2[k];
    }
}

static inline size_t align256(size_t x) { return (x + 255) & ~size_t(255); }

extern "C" void kernel_launch(void* const* d_in, const int* in_sizes, int n_in,
                              void* d_out, int out_size, void* d_ws, size_t ws_size,
                              hipStream_t stream) {
    const float* x  = (const float*)d_in[0];
    const int* edge = (const int*)d_in[1];
    const float* W1 = (const float*)d_in[2];
    const float* b1 = (const float*)d_in[3];
    const float* W2 = (const float*)d_in[4];
    const float* b2 = (const float*)d_in[5];
    float* out = (float*)d_out;

    const int E = in_sizes[1] / 2;
    const int* src = edge;
    const int* dst = edge + E;

    // workspace layout (~38 MB)
    char* ws = (char*)d_ws;
    size_t o = 0;
    unsigned int* gcnt    = (unsigned int*)(ws + o); o += align256((size_t)NBINS * GSTRIDE * 4);
    float* dinv           = (float*)(ws + o);        o += align256((size_t)N_NODES * 4);
    unsigned int* entries = (unsigned int*)(ws + o); o += align256((size_t)NBINS * CAPB * 4);
    unsigned int* noffg   = (unsigned int*)(ws + o); o += align256((size_t)NBINS * (NPB + 1) * 4);
    unsigned short* hs    = (unsigned short*)(ws + o); o += align256((size_t)N_NODES * F1 * 2);
    unsigned short* out1  = (unsigned short*)(ws + o); o += align256((size_t)N_NODES * F1 * 2);
    unsigned short* h2s   = (unsigned short*)(ws + o); o += align256((size_t)N_NODES * F2 * 2);

    hipMemsetAsync(gcnt, 0, (size_t)NBINS * GSTRIDE * 4, stream);

    k_bin<<<(E + TILE - 1) / TILE, 1024, 0, stream>>>(src, dst, E, gcnt, entries);

    // layer 1 (dinv fused into k_xw1; agg1 persists sorted CSR)
    k_xw1<<<NBINS, 512, 0, stream>>>(x, W1, gcnt, entries, dinv, hs);
    k_agg1f<<<NBINS, 1024, 0, stream>>>(gcnt, entries, noffg, hs, dinv, out1);

    // layer 2 (agg2 consumes saved CSR)
    k_xw2<<<(N_NODES + 127) / 128, 256, 0, stream>>>(out1, b1, W2, dinv, h2s);
    k_agg2f<<<NBINS, 1024, 0, stream>>>(gcnt, entries, noffg, h2s, dinv, b2, out);
}